// Round 11
// baseline (792.684 us; speedup 1.0000x reference)
//
#include <hip/hip_runtime.h>
#include <hip/hip_bf16.h>
#include <stdint.h>

typedef __attribute__((ext_vector_type(8))) short short8;  // 8 x bf16 MFMA operand
typedef __attribute__((ext_vector_type(4))) float f32x4;   // MFMA accumulator
typedef __attribute__((ext_vector_type(4))) float f32x4v;  // packed 4x f32
typedef __attribute__((ext_vector_type(2))) float f32x2;   // packed 2x f32 (v_pk_fma_f32)

#define DEV static __device__ __forceinline__

// ---- 32-lane (half-wave) sum-reduce via DPP, broadcast to own half ----
DEV float half_red_bcast(float x) {
  int t;
  t = __builtin_amdgcn_update_dpp(0, __float_as_int(x), 0x111, 0xf, 0xf, true); x += __int_as_float(t); // row_shr:1
  t = __builtin_amdgcn_update_dpp(0, __float_as_int(x), 0x112, 0xf, 0xf, true); x += __int_as_float(t); // row_shr:2
  t = __builtin_amdgcn_update_dpp(0, __float_as_int(x), 0x114, 0xf, 0xf, true); x += __int_as_float(t); // row_shr:4
  t = __builtin_amdgcn_update_dpp(0, __float_as_int(x), 0x118, 0xf, 0xf, true); x += __int_as_float(t); // row_shr:8
  t = __builtin_amdgcn_update_dpp(0, __float_as_int(x), 0x142, 0xa, 0xf, true); x += __int_as_float(t); // row_bcast:15 -> rows 1,3
  return __int_as_float(__builtin_amdgcn_ds_swizzle(__float_as_int(x), 0x3E0)); // all <- lane31 of own half
}

DEV void gload16(const void* g, void* lds) {
  __builtin_amdgcn_global_load_lds(
      (const __attribute__((address_space(1))) void*)g,
      (__attribute__((address_space(3))) void*)lds, 16, 0, 0);
}

#define LOG2E 1.44269504088896340736f

// ============================ prep ============================================
// blocks 0-3: q -> wq[h] (pre-scaled by log2(e))
// blocks [4, 4+nb): segment boundary scan -> starts[B+1]
// blocks [4+nb, ...): zero Sacc/dacc span (graph-replay safe re-init)
__global__ __launch_bounds__(256) void k_prep(
    const float* __restrict__ query, const float* __restrict__ in_w,
    const float* __restrict__ in_b, const int* __restrict__ seg,
    float* __restrict__ wq_ws, int* __restrict__ starts,
    float* __restrict__ zbase, int nzf4, int nb, int N, int B)
{
  __shared__ float sh[256];
  int t = threadIdx.x, bid = blockIdx.x;
  if (bid < 4) {
    float acc = in_b[t];
    for (int c = 0; c < 256; ++c) acc += query[c] * in_w[t * 256 + c];
    sh[t] = acc * 0.125f;                       // q[t]
    __syncthreads();
    int h = bid;
    float a = 0.f;
    for (int j = 0; j < 64; ++j) a += sh[64 * h + j] * in_w[(256 + 64 * h + j) * 256 + t];
    wq_ws[h * 256 + t] = a * LOG2E;             // exp2-domain
  } else if (bid < 4 + nb) {
    int idx = (bid - 4) * 256 + t;
    if (idx < N) {
      int s = seg[idx];
      int prev = (idx == 0) ? -1 : seg[idx - 1];
      for (int x = prev + 1; x <= s; ++x) starts[x] = idx;
      if (idx == N - 1) for (int x = s + 1; x <= B; ++x) starts[x] = N;
    }
  } else {
    int z = bid - (4 + nb);
    f32x4v zz = {0.f, 0.f, 0.f, 0.f};
    f32x4v* dst = (f32x4v*)zbase + (size_t)z * 1024;
    #pragma unroll
    for (int j = 0; j < 4; ++j) {
      int slot = j * 256 + t;
      if ((size_t)z * 1024 + slot < (size_t)nzf4) dst[slot] = zz;
    }
  }
}

// ================== streaming pass: contiguous 64-node tile per wave ==========
// Blocks [0, 257): input-only mtt/btot precompute (front-placed, hidden).
// Blocks [257, 257+N/256): 4 waves/block, each wave owns 64 CONTIGUOUS nodes
// (perfectly balanced & sequential). Halves interleave even/odd nodes
// (8 dims/lane, f32x2 packed, 2-deep prefetch — identical math to proven
// kernel). Per half: accumulate (d,S) per run of equal segment id; on segment
// change, atomicAdd-flush into zeroed f32 accumulators (no-max exp2 makes
// segment sums order-free; <=4 contributors per address).
__global__ __launch_bounds__(256, 5) void k_stream(
    const float* __restrict__ emb, const int* __restrict__ seg,
    const float* __restrict__ wq_ws,
    float* __restrict__ Sacc, float* __restrict__ dacc, int Nm1,
    const float* __restrict__ in_w, const float* __restrict__ in_b,
    const float* __restrict__ Wo, const float* __restrict__ bo,
    const float* __restrict__ Wu, const float* __restrict__ bu,
    __hip_bfloat16* __restrict__ mtt, float* __restrict__ btot)
{
  __shared__ float sh[256];
  int t = threadIdx.x;

  if (blockIdx.x < 257u) {
    // ---------------- front blocks: mtt / btot (inputs-only) ----------------
    int bid = blockIdx.x;
    if (bid < 256) {
      int u = bid;
      float wc = 0.f;
      for (int o = 0; o < 256; ++o) wc += Wu[u * 256 + o] * Wo[o * 256 + t];
      sh[t] = wc;                                  // wcomb[u, t]
      __syncthreads();
      #pragma unroll
      for (int h = 0; h < 4; ++h) {
        float a = 0.f;
        for (int r = 0; r < 64; ++r) a += sh[64 * h + r] * in_w[(512 + 64 * h + r) * 256 + t];
        mtt[(size_t)u * 1024 + h * 256 + t] = __float2bfloat16(a);
      }
    } else {
      const float* bv = in_b + 512;
      float wob = 0.f;
      for (int c = 0; c < 256; ++c) wob += Wo[t * 256 + c] * bv[c];
      sh[t] = bo[t] + wob;
      __syncthreads();
      float a = bu[t];
      for (int o = 0; o < 256; ++o) a += Wu[t * 256 + o] * sh[o];
      btot[t] = a;
    }
    return;
  }

  int lane = t & 63;
  int g = lane >> 5, i = lane & 31, i8 = i * 8;
  size_t base = ((size_t)(blockIdx.x - 257) * 4 + (t >> 6)) * 64;

  // per-head weights as 4x f32x2 (packed)
  f32x2 w[4][4];
  #pragma unroll
  for (int h = 0; h < 4; ++h) {
    const f32x2* wp = (const f32x2*)(wq_ws + h * 256 + i8);
    #pragma unroll
    for (int j = 0; j < 4; ++j) w[h][j] = wp[j];
  }

  float d[4] = {0.f, 0.f, 0.f, 0.f};
  f32x2 S[4][4] = {};

#define FLUSH(csv)                                                          \
  { float* Sb = Sacc + (size_t)(csv) * 1024 + i8;                           \
    _Pragma("unroll")                                                       \
    for (int h = 0; h < 4; ++h)                                             \
      _Pragma("unroll")                                                     \
      for (int j = 0; j < 4; ++j) {                                         \
        atomicAdd(Sb + h * 256 + 2 * j,     S[h][j].x);                     \
        atomicAdd(Sb + h * 256 + 2 * j + 1, S[h][j].y);                     \
        S[h][j] = (f32x2){0.f, 0.f};                                        \
      }                                                                     \
    if (i == 0) {                                                           \
      _Pragma("unroll")                                                     \
      for (int h = 0; h < 4; ++h) atomicAdd(dacc + (size_t)(csv) * 4 + h, d[h]); \
    }                                                                       \
    d[0] = d[1] = d[2] = d[3] = 0.f; }

  // 2-deep prefetch pipeline (rows + seg ids)
  size_t r0 = base + g, r1 = base + 2 + g;
  const float* p0 = emb + r0 * 256 + i8;
  const float* p1 = emb + r1 * 256 + i8;
  f32x4v c0 = *(const f32x4v*)p0, c1 = *(const f32x4v*)(p0 + 4);
  f32x4v n10 = *(const f32x4v*)p1, n11 = *(const f32x4v*)(p1 + 4);
  int cs = seg[r0];          // segment of accumulated state
  int scur = cs;             // segment of current node
  int snxt = seg[r1];

  for (int p = 0; p < 64; p += 2) {
    size_t rn = base + p + 4 + g; if (rn > (size_t)Nm1) rn = (size_t)Nm1;
    const float* np = emb + rn * 256 + i8;
    f32x4v L0 = *(const f32x4v*)np, L1 = *(const f32x4v*)(np + 4);
    int s2 = seg[rn];

    f32x2 c0l = __builtin_shufflevector(c0, c0, 0, 1);
    f32x2 c0h = __builtin_shufflevector(c0, c0, 2, 3);
    f32x2 c1l = __builtin_shufflevector(c1, c1, 0, 1);
    f32x2 c1h = __builtin_shufflevector(c1, c1, 2, 3);

    f32x2 P0 = c0l * w[0][0] + c0h * w[0][1] + c1l * w[0][2] + c1h * w[0][3];
    f32x2 P1 = c0l * w[1][0] + c0h * w[1][1] + c1l * w[1][2] + c1h * w[1][3];
    f32x2 P2 = c0l * w[2][0] + c0h * w[2][1] + c1l * w[2][2] + c1h * w[2][3];
    f32x2 P3 = c0l * w[3][0] + c0h * w[3][1] + c1l * w[3][2] + c1h * w[3][3];

    float s0 = half_red_bcast(P0.x + P0.y);
    float s1 = half_red_bcast(P1.x + P1.y);
    float s2f = half_red_bcast(P2.x + P2.y);
    float s3 = half_red_bcast(P3.x + P3.y);

    if (scur != cs) {        // half-uniform branch; rare (~1 in 10 iters)
      FLUSH(cs);
      cs = scur;
    }

    float e0 = __builtin_exp2f(s0);  d[0] += e0;
    float e1 = __builtin_exp2f(s1);  d[1] += e1;
    float e2 = __builtin_exp2f(s2f); d[2] += e2;
    float e3 = __builtin_exp2f(s3);  d[3] += e3;

#define ACC(h, e)                                                           \
    { f32x2 ev = {e, e};                                                    \
      S[h][0] += ev * c0l; S[h][1] += ev * c0h;                             \
      S[h][2] += ev * c1l; S[h][3] += ev * c1h; }
    ACC(0, e0) ACC(1, e1) ACC(2, e2) ACC(3, e3)
#undef ACC

    c0 = n10; c1 = n11; n10 = L0; n11 = L1;
    scur = snxt; snxt = s2;
  }

  FLUSH(cs);
#undef FLUSH
}

// =============== normalize: T[b] = Sacc[b]/d (bf16), mask ====================
// T is ALIASED over the low 2KB of each segment's 4KB Sacc row (read-before-
// write within the owning wave; per-b exclusive). Wave per segment.
__global__ __launch_bounds__(256) void k_norm(
    float* __restrict__ Sacc, const float* __restrict__ dacc,
    const int* __restrict__ starts, float* __restrict__ mask, int B)
{
  int t = threadIdx.x;
  int b = blockIdx.x * 4 + (t >> 6);
  if (b >= B) return;
  int lane = t & 63;
  char* Trow = (char*)Sacc + (size_t)b * 4096;
  int len = starts[b + 1] - starts[b];
  if (len == 0) {
    if (lane == 0) mask[b] = 0.f;
    uint4 z = {0u, 0u, 0u, 0u};
    *(uint4*)(Trow + lane * 32) = z;
    *(uint4*)(Trow + lane * 32 + 16) = z;
    return;
  }
  if (lane == 0) mask[b] = 1.f;
  const float* Sb = Sacc + (size_t)b * 1024;
  float4 v[4]; float den[4];
  #pragma unroll
  for (int h = 0; h < 4; ++h) {
    v[h] = *(const float4*)(Sb + h * 256 + lane * 4);
    den[h] = dacc[(size_t)b * 4 + h];
  }
  #pragma unroll
  for (int h = 0; h < 4; ++h) {
    float inv = 1.f / den[h];
    union { __hip_bfloat16 q[4]; uint2 u; } pk;
    pk.q[0] = __float2bfloat16(v[h].x * inv);
    pk.q[1] = __float2bfloat16(v[h].y * inv);
    pk.q[2] = __float2bfloat16(v[h].z * inv);
    pk.q[3] = __float2bfloat16(v[h].w * inv);
    *(uint2*)(Trow + (h * 256 + lane * 4) * 2) = pk.u;
  }
}

// ============ output GEMM: out(B,256) = T(B,1024) @ MtT(256,1024)^T ==========
// (R10 proven dbuf 2-phase version; T rows now at stride 4096 B inside Sacc.)
__global__ __launch_bounds__(256) void k_out(
    const float* __restrict__ Sacc, const __hip_bfloat16* __restrict__ mtt,
    const float* __restrict__ btot, const float* __restrict__ mask,
    float* __restrict__ out)
{
  __shared__ __align__(16) char smem[32768];   // [buf 16KB][A 8KB | B 8KB]
  int t = threadIdx.x;
  int l = t & 63, w = t >> 6;
  int wr = w >> 1, wc = w & 1;
  int tileM = blockIdx.x * 64, tileN = blockIdx.y * 64;

  const char* Tb = (const char*)Sacc;  // bf16 row at byte b*4096, 2048B used
  const char* Mb = (const char*)mtt;   // row stride 2048 B
  int chunk = (l & 7) ^ ((l >> 3) & 7);      // inverse-swizzled source chunk

  const char* aSrc[2]; const char* bSrc[2]; int ldsOff[2];
  #pragma unroll
  for (int i = 0; i < 2; ++i) {
    int row = (w * 2 + i) * 8 + (l >> 3);
    aSrc[i] = Tb + (size_t)(tileM + row) * 4096 + chunk * 16;
    bSrc[i] = Mb + (size_t)(tileN + row) * 2048 + chunk * 16;
    ldsOff[i] = (w * 2 + i) * 1024;
  }

  f32x4 acc[2][2] = {};

#define STAGE(step, base)                                                   \
  { int kb = (step) * 128;                                                  \
    _Pragma("unroll")                                                       \
    for (int i = 0; i < 2; ++i) {                                           \
      gload16(aSrc[i] + kb, smem + (base) + ldsOff[i]);                     \
      gload16(bSrc[i] + kb, smem + (base) + 8192 + ldsOff[i]);              \
    } }

  STAGE(0, 0);
  __syncthreads();

  int dbuf = 0;
  for (int step = 0; step < 16; ++step) {
    int base = dbuf << 14;
    if (step + 1 < 16) STAGE(step + 1, base ^ 16384);
    const char* As = smem + base;
    const char* Bs = smem + base + 8192;
    #pragma unroll
    for (int ks = 0; ks < 64; ks += 32) {
      short8 a[2], bf[2];
      int kbyte = (ks + (l >> 4) * 8) * 2;
      #pragma unroll
      for (int i = 0; i < 2; ++i) {
        int row = wr * 32 + i * 16 + (l & 15);
        a[i] = *(const short8*)(As + row * 128 + (kbyte ^ ((row & 7) << 4)));
        int crow = wc * 32 + i * 16 + (l & 15);
        bf[i] = *(const short8*)(Bs + crow * 128 + (kbyte ^ ((crow & 7) << 4)));
      }
      #pragma unroll
      for (int i = 0; i < 2; ++i)
        #pragma unroll
        for (int j = 0; j < 2; ++j)
          acc[i][j] = __builtin_amdgcn_mfma_f32_16x16x32_bf16(a[i], bf[j], acc[i][j], 0, 0, 0);
    }
    __syncthreads();   // drains stage(t+1) vmcnt + protects buf reuse
    dbuf ^= 1;
  }
#undef STAGE

  int cl = l & 15, rq = l >> 4;
  #pragma unroll
  for (int i = 0; i < 2; ++i)
    #pragma unroll
    for (int j = 0; j < 2; ++j) {
      int cg = tileN + wc * 32 + j * 16 + cl;
      float bt = btot[cg];
      #pragma unroll
      for (int r = 0; r < 4; ++r) {
        int rg = tileM + wr * 32 + i * 16 + rq * 4 + r;
        out[(size_t)rg * 256 + cg] = mask[rg] * (acc[i][j][r] + bt);
      }
    }
}

extern "C" void kernel_launch(void* const* d_in, const int* in_sizes, int n_in,
                              void* d_out, int out_size, void* d_ws, size_t ws_size,
                              hipStream_t stream) {
  const float* emb   = (const float*)d_in[0];
  const float* query = (const float*)d_in[1];
  const float* in_w  = (const float*)d_in[2];
  const float* in_b  = (const float*)d_in[3];
  const float* out_w = (const float*)d_in[4];  // Wo
  const float* out_b = (const float*)d_in[5];  // bo
  const float* up_w  = (const float*)d_in[6];  // Wu
  const float* up_b  = (const float*)d_in[7];  // bu
  const int*   seg   = (const int*)d_in[8];

  int N = in_sizes[0] / 256;
  int B = out_size / 256;

  char* wsb = (char*)d_ws;
  float* wq_ws  = (float*)(wsb + 0);              // 1024 f32
  int*   starts = (int*)(wsb + 8192);             // B+1 int
  float* maskp  = (float*)(wsb + 49152);          // B f32
  float* btot   = (float*)(wsb + 81920);          // 256 f32
  __hip_bfloat16* mtt = (__hip_bfloat16*)(wsb + 86016);   // 256x1024 bf16
  float* Sacc   = (float*)(wsb + 1048576);        // B x 1024 f32 (T bf16 aliased)
  float* dacc   = Sacc + (size_t)B * 1024;        // B x 4 f32 (contiguous after)

  int nb = (N + 255) / 256;
  size_t zbytes = (size_t)B * 1024 * 4 + (size_t)B * 4 * 4;   // Sacc + dacc
  int nzf4 = (int)(zbytes / 16);
  int nzb = (int)((zbytes + 16383) / 16384);

  k_prep<<<dim3(4 + nb + nzb), dim3(256), 0, stream>>>(
      query, in_w, in_b, seg, wq_ws, starts, Sacc, nzf4, nb, N, B);
  k_stream<<<dim3(257 + N / 256), dim3(256), 0, stream>>>(
      emb, seg, wq_ws, Sacc, dacc, N - 1,
      in_w, in_b, out_w, out_b, up_w, up_b, mtt, btot);
  k_norm<<<dim3((B + 3) / 4), dim3(256), 0, stream>>>(
      Sacc, dacc, starts, maskp, B);
  k_out<<<dim3(B / 64, 4), dim3(256), 0, stream>>>(
      Sacc, mtt, btot, maskp, (float*)d_out);
}

// Round 12
// 81.621 us; speedup vs baseline: 9.7118x; 9.7118x over previous
//
#include <hip/hip_runtime.h>
#include <hip/hip_bf16.h>
#include <stdint.h>

typedef __attribute__((ext_vector_type(8))) short short8;  // 8 x bf16 MFMA operand
typedef __attribute__((ext_vector_type(4))) float f32x4;   // MFMA accumulator
typedef __attribute__((ext_vector_type(4))) float f32x4v;  // packed 4x f32
typedef __attribute__((ext_vector_type(2))) float f32x2;   // packed 2x f32 (v_pk_fma_f32)

#define DEV static __device__ __forceinline__

// ---- 32-lane (half-wave) sum-reduce via DPP, broadcast to own half ----
DEV float half_red_bcast(float x) {
  int t;
  t = __builtin_amdgcn_update_dpp(0, __float_as_int(x), 0x111, 0xf, 0xf, true); x += __int_as_float(t); // row_shr:1
  t = __builtin_amdgcn_update_dpp(0, __float_as_int(x), 0x112, 0xf, 0xf, true); x += __int_as_float(t); // row_shr:2
  t = __builtin_amdgcn_update_dpp(0, __float_as_int(x), 0x114, 0xf, 0xf, true); x += __int_as_float(t); // row_shr:4
  t = __builtin_amdgcn_update_dpp(0, __float_as_int(x), 0x118, 0xf, 0xf, true); x += __int_as_float(t); // row_shr:8
  t = __builtin_amdgcn_update_dpp(0, __float_as_int(x), 0x142, 0xa, 0xf, true); x += __int_as_float(t); // row_bcast:15 -> rows 1,3
  return __int_as_float(__builtin_amdgcn_ds_swizzle(__float_as_int(x), 0x3E0)); // all <- lane31 of own half
}

DEV void gload16(const void* g, void* lds) {
  __builtin_amdgcn_global_load_lds(
      (const __attribute__((address_space(1))) void*)g,
      (__attribute__((address_space(3))) void*)lds, 16, 0, 0);
}

#define LOG2E 1.44269504088896340736f

// ============================ prep (critical prefix only) =====================
// blocks 0-3: q (in-block) -> wq[h] (pre-scaled by log2(e))
// blocks 4+ : segment boundary scan -> starts[B+1]
// The per-head score constant ch = q_h . bk_h cancels (softmax shift-invariance).
__global__ __launch_bounds__(256) void k_prep(
    const float* __restrict__ query, const float* __restrict__ in_w,
    const float* __restrict__ in_b, const int* __restrict__ seg,
    float* __restrict__ wq_ws, int* __restrict__ starts, int N, int B)
{
  __shared__ float sh[256];
  int t = threadIdx.x, bid = blockIdx.x;
  if (bid < 4) {
    float acc = in_b[t];
    for (int c = 0; c < 256; ++c) acc += query[c] * in_w[t * 256 + c];
    sh[t] = acc * 0.125f;                       // q[t]
    __syncthreads();
    int h = bid;
    float a = 0.f;
    for (int j = 0; j < 64; ++j) a += sh[64 * h + j] * in_w[(256 + 64 * h + j) * 256 + t];
    wq_ws[h * 256 + t] = a * LOG2E;             // exp2-domain
  } else {
    int idx = (bid - 4) * 256 + t;
    if (idx < N) {
      int s = seg[idx];
      int prev = (idx == 0) ? -1 : seg[idx - 1];
      for (int x = prev + 1; x <= s; ++x) starts[x] = idx;
      if (idx == N - 1) for (int x = s + 1; x <= B; ++x) starts[x] = N;
    }
  }
}

// ========== main: per-segment no-max softmax + weighted embedding sum =========
// (R6 proven structure.) Blocks [0, 257): input-only mtt/btot precompute,
// front-placed so they hide under the streaming phase. Blocks [257, 257+nB):
// 4 waves/block, ONE WAVE PER SEGMENT; each 32-lane half owns one node/iter
// (8 dims/lane, f32x2 packed); no-max exp2 softmax (scores bounded;
// shift-invariance exact); 2-deep row prefetch. VGPR must stay <=64.
__global__ __launch_bounds__(256, 4) void k_segattn(
    const float* __restrict__ emb, const int* __restrict__ starts,
    const float* __restrict__ wq_ws,
    float* __restrict__ mask, __hip_bfloat16* __restrict__ T, int B,
    const float* __restrict__ in_w, const float* __restrict__ in_b,
    const float* __restrict__ Wo, const float* __restrict__ bo,
    const float* __restrict__ Wu, const float* __restrict__ bu,
    __hip_bfloat16* __restrict__ mtt, float* __restrict__ btot)
{
  __shared__ float sh[256];
  int t = threadIdx.x;

  if (blockIdx.x < 257u) {
    // ---------------- front blocks: mtt / btot (inputs-only) ----------------
    int bid = blockIdx.x;
    if (bid < 256) {
      int u = bid;
      float wc = 0.f;
      for (int o = 0; o < 256; ++o) wc += Wu[u * 256 + o] * Wo[o * 256 + t];
      sh[t] = wc;                                  // wcomb[u, t]
      __syncthreads();
      #pragma unroll
      for (int h = 0; h < 4; ++h) {
        float a = 0.f;
        for (int r = 0; r < 64; ++r) a += sh[64 * h + r] * in_w[(512 + 64 * h + r) * 256 + t];
        mtt[(size_t)u * 1024 + h * 256 + t] = __float2bfloat16(a);
      }
    } else {
      const float* bv = in_b + 512;
      float wob = 0.f;
      for (int c = 0; c < 256; ++c) wob += Wo[t * 256 + c] * bv[c];
      sh[t] = bo[t] + wob;
      __syncthreads();
      float a = bu[t];
      for (int o = 0; o < 256; ++o) a += Wu[t * 256 + o] * sh[o];
      btot[t] = a;
    }
    return;
  }

  int lane = t & 63;
  int g = lane >> 5, i = lane & 31, i8 = i * 8;
  int b = (blockIdx.x - 257) * 4 + (t >> 6);
  if (b >= B) return;
  int start = starts[b], end = starts[b + 1];
  __hip_bfloat16* Tb = T + (size_t)b * 1024;

  if (start >= end) {
    if (lane == 0) mask[b] = 0.f;
    if (lane < 32) {
      uint4 z = {0u, 0u, 0u, 0u};
      *(uint4*)(Tb + 0 * 256 + lane * 8) = z;
      *(uint4*)(Tb + 1 * 256 + lane * 8) = z;
      *(uint4*)(Tb + 2 * 256 + lane * 8) = z;
      *(uint4*)(Tb + 3 * 256 + lane * 8) = z;
    }
    return;
  }
  if (lane == 0) mask[b] = 1.f;

  // per-head weights as 4x f32x2 (packed)
  f32x2 w[4][4];
  #pragma unroll
  for (int h = 0; h < 4; ++h) {
    const f32x2* wp = (const f32x2*)(wq_ws + h * 256 + i8);
    #pragma unroll
    for (int j = 0; j < 4; ++j) w[h][j] = wp[j];
  }

  float d[4] = {0.f, 0.f, 0.f, 0.f};
  f32x2 S[4][4] = {};

  // 2-deep prefetch pipeline
  int r0 = start + g;     if (r0 > end - 1) r0 = end - 1;
  int r1 = start + 2 + g; if (r1 > end - 1) r1 = end - 1;
  const float* p0 = emb + (size_t)r0 * 256 + i8;
  const float* p1 = emb + (size_t)r1 * 256 + i8;
  f32x4v c0 = *(const f32x4v*)p0, c1 = *(const f32x4v*)(p0 + 4);
  f32x4v n10 = *(const f32x4v*)p1, n11 = *(const f32x4v*)(p1 + 4);

  for (int p = start; p < end; p += 2) {
    int rn = p + 4 + g; if (rn > end - 1) rn = end - 1;
    const float* np = emb + (size_t)rn * 256 + i8;
    f32x4v L0 = *(const f32x4v*)np, L1 = *(const f32x4v*)(np + 4);

    f32x2 c0l = __builtin_shufflevector(c0, c0, 0, 1);
    f32x2 c0h = __builtin_shufflevector(c0, c0, 2, 3);
    f32x2 c1l = __builtin_shufflevector(c1, c1, 0, 1);
    f32x2 c1h = __builtin_shufflevector(c1, c1, 2, 3);

    f32x2 P0 = c0l * w[0][0] + c0h * w[0][1] + c1l * w[0][2] + c1h * w[0][3];
    f32x2 P1 = c0l * w[1][0] + c0h * w[1][1] + c1l * w[1][2] + c1h * w[1][3];
    f32x2 P2 = c0l * w[2][0] + c0h * w[2][1] + c1l * w[2][2] + c1h * w[2][3];
    f32x2 P3 = c0l * w[3][0] + c0h * w[3][1] + c1l * w[3][2] + c1h * w[3][3];

    float s0 = half_red_bcast(P0.x + P0.y);
    float s1 = half_red_bcast(P1.x + P1.y);
    float s2 = half_red_bcast(P2.x + P2.y);
    float s3 = half_red_bcast(P3.x + P3.y);

    if ((p + g) >= end) { s0 = -1e30f; s1 = -1e30f; s2 = -1e30f; s3 = -1e30f; }

    float e0 = __builtin_exp2f(s0); d[0] += e0;
    float e1 = __builtin_exp2f(s1); d[1] += e1;
    float e2 = __builtin_exp2f(s2); d[2] += e2;
    float e3 = __builtin_exp2f(s3); d[3] += e3;

#define ACC(h, e)                                                           \
    { f32x2 ev = {e, e};                                                    \
      S[h][0] += ev * c0l; S[h][1] += ev * c0h;                             \
      S[h][2] += ev * c1l; S[h][3] += ev * c1h; }
    ACC(0, e0) ACC(1, e1) ACC(2, e2) ACC(3, e3)
#undef ACC

    c0 = n10; c1 = n11; n10 = L0; n11 = L1;
  }

  // merge halves: d_total = d + other-half d; scale; cross-sum; store bf16
#define FIN(h)                                                              \
  { float od = __shfl_xor(d[h], 32);                                        \
    float sc = 1.f / (d[h] + od);                                           \
    float t0 = S[h][0].x * sc, t1 = S[h][0].y * sc;                         \
    float t2 = S[h][1].x * sc, t3 = S[h][1].y * sc;                         \
    float t4 = S[h][2].x * sc, t5 = S[h][2].y * sc;                         \
    float t6 = S[h][3].x * sc, t7 = S[h][3].y * sc;                         \
    t0 += __shfl_xor(t0, 32); t1 += __shfl_xor(t1, 32);                     \
    t2 += __shfl_xor(t2, 32); t3 += __shfl_xor(t3, 32);                     \
    t4 += __shfl_xor(t4, 32); t5 += __shfl_xor(t5, 32);                     \
    t6 += __shfl_xor(t6, 32); t7 += __shfl_xor(t7, 32);                     \
    if (g == 0) {                                                           \
      union { __hip_bfloat16 v[8]; uint4 u; } pk;                           \
      pk.v[0] = __float2bfloat16(t0); pk.v[1] = __float2bfloat16(t1);       \
      pk.v[2] = __float2bfloat16(t2); pk.v[3] = __float2bfloat16(t3);       \
      pk.v[4] = __float2bfloat16(t4); pk.v[5] = __float2bfloat16(t5);       \
      pk.v[6] = __float2bfloat16(t6); pk.v[7] = __float2bfloat16(t7);       \
      *(uint4*)(Tb + h * 256 + i8) = pk.u; } }
  FIN(0) FIN(1) FIN(2) FIN(3)
#undef FIN
}

// ============ output GEMM: out(B,256) = T(B,1024) @ MtT(256,1024)^T ==========
// bf16 MFMA 16x16x32, 64x64 tile, 4 waves (2x2), XOR-swizzled LDS,
// global_load_lds(width=16), DOUBLE-BUFFERED 2-phase: stage(t+1) issued
// BEFORE compute(t), one barrier per K-step (T3 minimum). Grid transposed
// (x = M-tile): row-panel partners 128 apart -> same XCD -> T L2 reuse.
__global__ __launch_bounds__(256) void k_out(
    const __hip_bfloat16* __restrict__ T, const __hip_bfloat16* __restrict__ mtt,
    const float* __restrict__ btot, const float* __restrict__ mask,
    float* __restrict__ out)
{
  __shared__ __align__(16) char smem[32768];   // [buf 16KB][A 8KB | B 8KB]
  int t = threadIdx.x;
  int l = t & 63, w = t >> 6;
  int wr = w >> 1, wc = w & 1;
  int tileM = blockIdx.x * 64, tileN = blockIdx.y * 64;

  const char* Tb = (const char*)T;     // row stride 2048 B
  const char* Mb = (const char*)mtt;   // row stride 2048 B
  int chunk = (l & 7) ^ ((l >> 3) & 7);      // inverse-swizzled source chunk

  const char* aSrc[2]; const char* bSrc[2]; int ldsOff[2];
  #pragma unroll
  for (int i = 0; i < 2; ++i) {
    int row = (w * 2 + i) * 8 + (l >> 3);
    aSrc[i] = Tb + (size_t)(tileM + row) * 2048 + chunk * 16;
    bSrc[i] = Mb + (size_t)(tileN + row) * 2048 + chunk * 16;
    ldsOff[i] = (w * 2 + i) * 1024;
  }

  f32x4 acc[2][2] = {};

#define STAGE(step, base)                                                   \
  { int kb = (step) * 128;                                                  \
    _Pragma("unroll")                                                       \
    for (int i = 0; i < 2; ++i) {                                           \
      gload16(aSrc[i] + kb, smem + (base) + ldsOff[i]);                     \
      gload16(bSrc[i] + kb, smem + (base) + 8192 + ldsOff[i]);              \
    } }

  STAGE(0, 0);
  __syncthreads();

  int dbuf = 0;
  for (int step = 0; step < 16; ++step) {
    int base = dbuf << 14;
    if (step + 1 < 16) STAGE(step + 1, base ^ 16384);
    const char* As = smem + base;
    const char* Bs = smem + base + 8192;
    #pragma unroll
    for (int ks = 0; ks < 64; ks += 32) {
      short8 a[2], bf[2];
      int kbyte = (ks + (l >> 4) * 8) * 2;
      #pragma unroll
      for (int i = 0; i < 2; ++i) {
        int row = wr * 32 + i * 16 + (l & 15);
        a[i] = *(const short8*)(As + row * 128 + (kbyte ^ ((row & 7) << 4)));
        int crow = wc * 32 + i * 16 + (l & 15);
        bf[i] = *(const short8*)(Bs + crow * 128 + (kbyte ^ ((crow & 7) << 4)));
      }
      #pragma unroll
      for (int i = 0; i < 2; ++i)
        #pragma unroll
        for (int j = 0; j < 2; ++j)
          acc[i][j] = __builtin_amdgcn_mfma_f32_16x16x32_bf16(a[i], bf[j], acc[i][j], 0, 0, 0);
    }
    __syncthreads();   // drains stage(t+1) vmcnt + protects buf reuse
    dbuf ^= 1;
  }
#undef STAGE

  int cl = l & 15, rq = l >> 4;
  #pragma unroll
  for (int i = 0; i < 2; ++i)
    #pragma unroll
    for (int j = 0; j < 2; ++j) {
      int cg = tileN + wc * 32 + j * 16 + cl;
      float bt = btot[cg];
      #pragma unroll
      for (int r = 0; r < 4; ++r) {
        int rg = tileM + wr * 32 + i * 16 + rq * 4 + r;
        out[(size_t)rg * 256 + cg] = mask[rg] * (acc[i][j][r] + bt);
      }
    }
}

extern "C" void kernel_launch(void* const* d_in, const int* in_sizes, int n_in,
                              void* d_out, int out_size, void* d_ws, size_t ws_size,
                              hipStream_t stream) {
  const float* emb   = (const float*)d_in[0];
  const float* query = (const float*)d_in[1];
  const float* in_w  = (const float*)d_in[2];
  const float* in_b  = (const float*)d_in[3];
  const float* out_w = (const float*)d_in[4];  // Wo
  const float* out_b = (const float*)d_in[5];  // bo
  const float* up_w  = (const float*)d_in[6];  // Wu
  const float* up_b  = (const float*)d_in[7];  // bu
  const int*   seg   = (const int*)d_in[8];

  int N = in_sizes[0] / 256;
  int B = out_size / 256;

  char* wsb = (char*)d_ws;
  float* wq_ws  = (float*)(wsb + 0);        // 1024 f32
  float* btot   = (float*)(wsb + 8192);     // 256 f32
  int*   starts = (int*)(wsb + 12288);      // B+1 int
  float* maskp  = (float*)(wsb + 45312);    // B f32
  __hip_bfloat16* mtt = (__hip_bfloat16*)(wsb + 78336);   // 256x1024 bf16
  __hip_bfloat16* Tp  = (__hip_bfloat16*)(wsb + 602624);  // B x 1024 bf16

  int nb_bounds = (N + 255) / 256;
  int nB = (B + 3) / 4;
  k_prep<<<dim3(4 + nb_bounds), dim3(256), 0, stream>>>(
      query, in_w, in_b, seg, wq_ws, starts, N, B);
  k_segattn<<<dim3(257 + nB), dim3(256), 0, stream>>>(
      emb, starts, wq_ws, maskp, Tp, B,
      in_w, in_b, out_w, out_b, up_w, up_b, mtt, btot);
  k_out<<<dim3(B / 64, 4), dim3(256), 0, stream>>>(Tp, mtt, btot, maskp, (float*)d_out);
}